// Round 9
// baseline (567.488 us; speedup 1.0000x reference)
//
#include <hip/hip_runtime.h>

// GraphConvGRU: B=16384, IN=32, HID=3, N=22 nodes, T=100 steps.
// Graph collapses to 3 node-equivalence classes -> per-chain state = 9 floats,
// reduced 3x3 adjacency (verified; R0-R3,R6-R8 passed, absmax 3.9e-3).
//
// R9 theory: device-wide STORE ADDRESS ORDER is the limiter.
//   All prior variants kept 16384 output rows open concurrently in ~1KB
//   pieces -> L2 eviction interleave -> shuffled HBM write stream -> 2.2 TB/s
//   (invariant across CU count, run length, barriers, occupancy, nt).
//   The 6.1 TB/s harness fill is a grid-stride DENSE MOVING WINDOW.
// Fix:
//   K1: recurrence -> compact, TIME-MAJOR [(t*B+b)*12+q], stored straight
//       from registers: whole device writes one dense 786KB t-slab at a time.
//   K2: grid-stride flat sweep of the 27M output f4s (1056 blk x 256 thr x
//       100 iters = exact cover): iteration k writes a dense 4.2MB window,
//       exactly the fill's pattern. Gather via u16 table (t<<4|cls); compact
//       is L3-resident.

#define B_TOT 16384
#define T_TOTAL 100
#define REC 12                       // floats per (t,b) record (9 used)
#define TSLAB (B_TOT * REC)          // 196608 floats per t-slab
#define CMP_FLOATS ((size_t)T_TOTAL * TSLAB)   // 19,660,800 floats = 78.6 MB

#define TPB1 64
#define GRID1 (B_TOT / TPB1)         // 256 blocks, 1 wave each

#define TPB2 256
#define GRID2 1056
#define ITERS2 100                   // 1056*256*100 = 27,033,600 = 16384*1650
#define SWEEP (GRID2 * TPB2)         // 270,336 f4 per window
#define OUT_ROW_F4 1650
#define OUT_ELEMS 6600

// fused fallback (R8 geometry, known-passing) if ws too small
#define FREP 8
#define FRPW (TPB1 / FREP)
#define FGRID (B_TOT / TPB1 * FREP)
#define FSCH 4
#define FNCHUNK (T_TOTAL / FSCH)
#define FROW_F4 (FSCH * 66 / 4)      // 66
#define FSTRIDE (FSCH * 9 + 1)       // 37
#define FSTG (TPB1 * FSTRIDE)
#define F4_PER_REP (FRPW * FROW_F4)  // 528
#define FGITERS ((F4_PER_REP + TPB1 - 1) / TPB1)  // 9

#if __has_builtin(__builtin_amdgcn_exp2f)
#define EXP2F __builtin_amdgcn_exp2f
#else
#define EXP2F exp2f
#endif
#if __has_builtin(__builtin_amdgcn_rcpf)
#define RCPF __builtin_amdgcn_rcpf
#else
#define RCPF(x) (1.0f / (x))
#endif

static __device__ __forceinline__ float fast_sigmoid(float x) {
    float e = EXP2F(-1.44269504f * x);
    return RCPF(1.0f + e);
}
static __device__ __forceinline__ float fast_tanh(float x) {
    float e = EXP2F(2.88539008f * x);          // exp(2x)
    return 1.0f - 2.0f * RCPF(1.0f + e);
}

// cls3[k] = class(node k/3)*3 + k%3 for k in [0,66)
__device__ const unsigned char d_cls3[66] = {
    0,1,2, 3,4,5, 3,4,5, 6,7,8, 3,4,5, 3,4,5, 6,7,8, 3,4,5, 3,4,5,
    0,1,2, 3,4,5, 3,4,5, 6,7,8, 3,4,5, 3,4,5, 6,7,8, 3,4,5, 3,4,5,
    3,4,5, 3,4,5, 3,4,5, 3,4,5
};

struct GruConsts {
    float xr[3], xz[3], xh[3];
    float W9[9], gb3[3];
};

static __device__ __forceinline__ void project_inputs(
    const float* __restrict__ x, int b,
    const float* __restrict__ wS,
    const float* __restrict__ w_r_b, const float* __restrict__ w_z_b,
    const float* __restrict__ w_h_b,
    const float* __restrict__ gcn_W, const float* __restrict__ gcn_b,
    GruConsts& C)
{
    float xv[32];
    const float4* xp = reinterpret_cast<const float4*>(x + (size_t)b * 32);
    #pragma unroll
    for (int i = 0; i < 8; ++i) {
        float4 v = xp[i];
        xv[4*i+0] = v.x; xv[4*i+1] = v.y; xv[4*i+2] = v.z; xv[4*i+3] = v.w;
    }
    #pragma unroll
    for (int j = 0; j < 3; ++j) { C.xr[j] = w_r_b[j]; C.xz[j] = w_z_b[j]; C.xh[j] = w_h_b[j]; }
    #pragma unroll
    for (int i = 0; i < 32; ++i) {
        float xi = xv[i];
        #pragma unroll
        for (int j = 0; j < 3; ++j) {
            C.xr[j] = fmaf(xi, wS[i*3+j],       C.xr[j]);
            C.xz[j] = fmaf(xi, wS[96 + i*3+j],  C.xz[j]);
            C.xh[j] = fmaf(xi, wS[192 + i*3+j], C.xh[j]);
        }
    }
    #pragma unroll
    for (int i = 0; i < 9; ++i) C.W9[i] = gcn_W[i];
    #pragma unroll
    for (int j = 0; j < 3; ++j) C.gb3[j] = gcn_b[j];
}

static __device__ __forceinline__ void gru_step(float* __restrict__ h, const GruConsts& C)
{
    // reduced symmetric-normalized adjacency (3 classes), exact:
    const float M00 = 0.0769230769f;   // 1/13
    const float M01 = 1.1094003925f;   // 4/sqrt(13)
    const float M02 = 0.4961389384f;   // 4/sqrt(65)
    const float M10 = 0.1386750491f;   // 1/(2 sqrt(13))
    const float M11 = 0.75f;
    const float M20 = 0.2480694691f;   // 2/sqrt(65)
    const float M22 = 0.6f;

    float mh[9], gh[9];
    #pragma unroll
    for (int j = 0; j < 3; ++j) {
        mh[j]     = M00 * h[j] + M01 * h[3+j] + M02 * h[6+j];
        mh[3 + j] = M10 * h[j] + M11 * h[3+j];
        mh[6 + j] = M20 * h[j] + M22 * h[6+j];
    }
    #pragma unroll
    for (int c = 0; c < 3; ++c)
        #pragma unroll
        for (int j = 0; j < 3; ++j)
            gh[c*3+j] = C.gb3[j] + mh[c*3+0]*C.W9[j] + mh[c*3+1]*C.W9[3+j] + mh[c*3+2]*C.W9[6+j];
    #pragma unroll
    for (int c = 0; c < 3; ++c) {
        #pragma unroll
        for (int j = 0; j < 3; ++j) {
            float g  = gh[c*3+j];
            float r  = fast_sigmoid(C.xr[j] + g);
            float z  = fast_sigmoid(C.xz[j] + g);
            float ht = fast_tanh(C.xh[j] + r * g);
            float hv = h[c*3+j];
            h[c*3+j] = hv + z * (ht - hv);
        }
    }
}

// ---------------- K1: recurrence -> time-major compact ----------------
__global__ __launch_bounds__(TPB1) void gcgru_compute(
    const float* __restrict__ x,
    const float* __restrict__ w_r_W, const float* __restrict__ w_r_b,
    const float* __restrict__ w_z_W, const float* __restrict__ w_z_b,
    const float* __restrict__ w_h_W, const float* __restrict__ w_h_b,
    const float* __restrict__ gcn_W, const float* __restrict__ gcn_b,
    float* __restrict__ compact)
{
    __shared__ float wS[288];

    const int tid = threadIdx.x;
    const int b   = blockIdx.x * TPB1 + tid;

    for (int i = tid; i < 96; i += TPB1) {
        wS[i]       = w_r_W[i];
        wS[96 + i]  = w_z_W[i];
        wS[192 + i] = w_h_W[i];
    }
    // single wave: DS in-order, no barrier (R3-validated)

    GruConsts C;
    project_inputs(x, b, wS, w_r_b, w_z_b, w_h_b, gcn_W, gcn_b, C);

    float h[9];
    #pragma unroll
    for (int i = 0; i < 9; ++i) h[i] = 0.0f;

    // time-major: at step t the whole device writes one dense 786KB slab
    for (int t = 0; t < T_TOTAL; ++t) {
        gru_step(h, C);
        size_t off = (size_t)t * TSLAB + (size_t)b * REC;
        float4 v0 = make_float4(h[0], h[1], h[2], h[3]);
        float4 v1 = make_float4(h[4], h[5], h[6], h[7]);
        *reinterpret_cast<float4*>(compact + off)     = v0;
        *reinterpret_cast<float4*>(compact + off + 4) = v1;
        compact[off + 8] = h[8];
    }
}

// ---------------- K2: dense grid-stride sweep expand ----------------
__global__ __launch_bounds__(TPB2) void gcgru_expand(
    const float* __restrict__ compact,
    float* __restrict__ out)
{
    __shared__ unsigned short tabE[OUT_ELEMS];   // (t<<4)|cls per output element

    const int tid = threadIdx.x;
    for (int jj = tid; jj < OUT_ELEMS; jj += TPB2) {
        int t = jj / 66;
        int k = jj - 66 * t;
        tabE[jj] = (unsigned short)((t << 4) | d_cls3[k]);
    }
    __syncthreads();

    float4* out4 = reinterpret_cast<float4*>(out);
    const unsigned base = blockIdx.x * TPB2 + tid;   // 0..SWEEP-1

    for (int it = 0; it < ITERS2; ++it) {
        unsigned idx = (unsigned)it * SWEEP + base;  // flat f4 index, dense window
        unsigned b   = idx / 1650u;                  // compiler magic-mul
        unsigned j4  = idx - b * 1650u;
        unsigned jj  = j4 * 4u;

        unsigned e0 = tabE[jj + 0];
        unsigned e1 = tabE[jj + 1];
        unsigned e2 = tabE[jj + 2];
        unsigned e3 = tabE[jj + 3];

        const float* cb = compact + (size_t)b * REC;
        float4 v;
        v.x = cb[(size_t)(e0 >> 4) * TSLAB + (e0 & 15u)];
        v.y = cb[(size_t)(e1 >> 4) * TSLAB + (e1 & 15u)];
        v.z = cb[(size_t)(e2 >> 4) * TSLAB + (e2 & 15u)];
        v.w = cb[(size_t)(e3 >> 4) * TSLAB + (e3 & 15u)];
        out4[idx] = v;
    }
}

// ---------------- fused fallback (R8, known-passing) if ws too small ----------------
__global__ __launch_bounds__(TPB1) void gcgru_fused(
    const float* __restrict__ x,
    const float* __restrict__ w_r_W, const float* __restrict__ w_r_b,
    const float* __restrict__ w_z_W, const float* __restrict__ w_z_b,
    const float* __restrict__ w_h_W, const float* __restrict__ w_h_b,
    const float* __restrict__ gcn_W, const float* __restrict__ gcn_b,
    float* __restrict__ out)
{
    __shared__ float stage[FSTG];
    __shared__ unsigned int tabS[FROW_F4];

    const int tid  = threadIdx.x;
    const int rep  = blockIdx.x & (FREP - 1);
    const int b0   = (blockIdx.x >> 3) * TPB1;
    const int row0 = rep * FRPW;

    for (int i = tid; i < 96; i += TPB1) {
        stage[i]       = w_r_W[i];
        stage[96 + i]  = w_z_W[i];
        stage[192 + i] = w_h_W[i];
    }
    for (int j4 = tid; j4 < FROW_F4; j4 += TPB1) {
        unsigned int w = 0;
        #pragma unroll
        for (int u = 0; u < 4; ++u) {
            int jj = 4 * j4 + u;
            int tl = jj / 66;
            int k  = jj - 66 * tl;
            w |= (unsigned int)(tl * 9 + d_cls3[k]) << (8 * u);
        }
        tabS[j4] = w;
    }

    GruConsts C;
    project_inputs(x, b0 + tid, stage, w_r_b, w_z_b, w_h_b, gcn_W, gcn_b, C);

    float h[9];
    #pragma unroll
    for (int i = 0; i < 9; ++i) h[i] = 0.0f;

    float4* out4 = reinterpret_cast<float4*>(out);

    for (int chunk = 0; chunk < FNCHUNK; ++chunk) {
        float* stw = stage + tid * FSTRIDE;
        #pragma unroll
        for (int s = 0; s < FSCH; ++s) {
            gru_step(h, C);
            #pragma unroll
            for (int q = 0; q < 9; ++q) stw[s*9 + q] = h[q];
        }
        const int cbase = chunk * FROW_F4;
        float4 vv[FGITERS];
        #pragma unroll
        for (int i = 0; i < FGITERS; ++i) {
            int f  = i * TPB1 + tid;
            int fi = (f < F4_PER_REP) ? f : 0;
            int rl = fi / FROW_F4;
            int j4 = fi - rl * FROW_F4;
            unsigned int tw = tabS[j4];
            const float* row = stage + (row0 + rl) * FSTRIDE;
            vv[i].x = row[tw & 255u];
            vv[i].y = row[(tw >> 8)  & 255u];
            vv[i].z = row[(tw >> 16) & 255u];
            vv[i].w = row[tw >> 24];
        }
        #pragma unroll
        for (int i = 0; i < FGITERS; ++i) {
            int f = i * TPB1 + tid;
            if (f < F4_PER_REP) {
                int rl = f / FROW_F4;
                int j4 = f - rl * FROW_F4;
                out4[(size_t)(b0 + row0 + rl) * OUT_ROW_F4 + cbase + j4] = vv[i];
            }
        }
    }
}

extern "C" void kernel_launch(void* const* d_in, const int* in_sizes, int n_in,
                              void* d_out, int out_size, void* d_ws, size_t ws_size,
                              hipStream_t stream) {
    const float* xp     = (const float*)d_in[0];
    const float* w_r_W  = (const float*)d_in[1];
    const float* w_r_b  = (const float*)d_in[2];
    const float* w_z_W  = (const float*)d_in[3];
    const float* w_z_b  = (const float*)d_in[4];
    const float* w_h_W  = (const float*)d_in[5];
    const float* w_h_b  = (const float*)d_in[6];
    const float* gcn_W  = (const float*)d_in[7];
    const float* gcn_b  = (const float*)d_in[8];
    float* outp = (float*)d_out;

    const size_t need = CMP_FLOATS * sizeof(float);   // 78.6 MB
    if (ws_size >= need && d_ws != nullptr) {
        float* compact = (float*)d_ws;
        gcgru_compute<<<GRID1, TPB1, 0, stream>>>(xp, w_r_W, w_r_b, w_z_W, w_z_b,
                                                  w_h_W, w_h_b, gcn_W, gcn_b, compact);
        gcgru_expand<<<GRID2, TPB2, 0, stream>>>(compact, outp);
    } else {
        gcgru_fused<<<FGRID, TPB1, 0, stream>>>(xp, w_r_W, w_r_b, w_z_W, w_z_b,
                                                w_h_W, w_h_b, gcn_W, gcn_b, outp);
    }
}